// Round 6
// baseline (451.681 us; speedup 1.0000x reference)
//
#include <hip/hip_runtime.h>
#include <stdint.h>

// Problem constants (from reference)
#define N_CLASSES  10
#define N_TREES    4000
#define DEPTH      6
#define N_INTERNAL 63
#define N_FEATURES 128
#define BATCH      32768
#define LR         0.1f

// Kernel config
#define BLOCK       256
#define SAMPLES_PB  32
#define TSPLIT      2                       // tree split across blockIdx.y
#define SLOTS_PB    (N_TREES / TSPLIT)      // 2000 class-grouped slots per block
#define T_TILE      16                      // slots per tile; first 8 staged to LDS
#define LDS_TREES   8                       // trees per tile served from LDS
#define N_TILES     (SLOTS_PB / T_TILE)     // 125
#define TILES_PER_CLASS 25                  // 400 trees/class / 16
#define SUMS_STRIDE 11

// ws layout: [0, 2.048MB) nodes by slot, INTERLEAVED: tree t -> 64 int2 of
// (feat, thr_bits); node n at int2 index n. [2.048MB, 3.072MB) leaves (64 f32).
// Slot permutation groups trees by class: slot = (t%10)*400 + t/10.
#define WS_NODES_BYTES  ((size_t)N_TREES * 64 * 8)
#define WS_LEAVES_BYTES ((size_t)N_TREES * 64 * 4)

__global__ void pack_kernel(const int* __restrict__ features,
                            const float* __restrict__ thresholds,
                            const float* __restrict__ leaves,
                            int2* __restrict__ pn, float* __restrict__ pl) {
    int i = blockIdx.x * blockDim.x + threadIdx.x;   // over N_TREES*64
    int t = i >> 6, n = i & 63;
    if (t < N_TREES) {
        int slot = (t % N_CLASSES) * (N_TREES / N_CLASSES) + (t / N_CLASSES);
        if (n < N_INTERNAL)
            pn[slot * 64 + n] = make_int2(features[t * N_INTERNAL + n],
                                          __float_as_int(thresholds[t * N_INTERNAL + n]));
        pl[slot * 64 + n] = leaves[t * 64 + n];
    }
}

__global__ void out_init_kernel(const float* __restrict__ init_out,
                                float* __restrict__ out) {
    int i = blockIdx.x * blockDim.x + threadIdx.x;
    if (i < BATCH * N_CLASSES) {
        int s = i / N_CLASSES;
        out[i] = init_out[i - s * N_CLASSES];
    }
}

// CK-style addrspace casts for global_load_lds (worked in R5).
__device__ __forceinline__ void load_lds_16(const void* g, void* l) {
    const auto* g1 = reinterpret_cast<const __attribute__((address_space(1))) uint32_t*>(
        reinterpret_cast<uintptr_t>(g));
    auto* l3 = reinterpret_cast<__attribute__((address_space(3))) uint32_t*>(
        reinterpret_cast<uintptr_t>(l));
    __builtin_amdgcn_global_load_lds(g1, l3, 16, 0, 0);
}

__global__ __launch_bounds__(BLOCK, 4) void gbt_eval(
    const float* __restrict__ x,
    const int2*  __restrict__ pnodes,   // [N_TREES][64] int2, class-grouped slots
    const float* __restrict__ pleaves,  // [N_TREES][64], class-grouped slots
    float*       __restrict__ out)      // [BATCH][10], pre-init to init_out
{
    __shared__ float xs[N_FEATURES * SAMPLES_PB];       // 16 KB, transposed
    __shared__ int2  nbuf[2][LDS_TREES * 64];           // 2 x 4 KB node tiles
    __shared__ float sums[SAMPLES_PB * SUMS_STRIDE];    // 1.4 KB

    const int tid = threadIdx.x;
    const int sample0 = blockIdx.x * SAMPLES_PB;
    const int slot0   = blockIdx.y * SLOTS_PB;
    const int cls0    = blockIdx.y * (N_CLASSES / TSPLIT);  // 5 classes per block

    // Stage x transposed: xs[f*32 + s]; hot-loop bank = s%32, conflict-free.
    {
        const float4* xg = (const float4*)(x + (size_t)sample0 * N_FEATURES);
        for (int e = tid; e < SAMPLES_PB * (N_FEATURES / 4); e += BLOCK) {
            int s = e >> 5, f4 = e & 31;
            float4 v = xg[e];
            int f = f4 << 2;
            xs[(f + 0) * SAMPLES_PB + s] = v.x;
            xs[(f + 1) * SAMPLES_PB + s] = v.y;
            xs[(f + 2) * SAMPLES_PB + s] = v.z;
            xs[(f + 3) * SAMPLES_PB + s] = v.w;
        }
    }
    for (int i = tid; i < SAMPLES_PB * SUMS_STRIDE; i += BLOCK) sums[i] = 0.f;

    const int lane = tid & 63;
    const int wv   = tid >> 6;          // wave id 0..3

    // Stage first LDS_TREES (=8) slots of a tile: 4 KB; each wave DMAs 1 KB.
    auto stage = [&](int tile, int b) {
        const char* g = (const char*)(pnodes + (size_t)(slot0 + tile * T_TILE) * 64);
        char* l = (char*)&nbuf[b][0];
        load_lds_16(g + wv * 1024 + lane * 16, l + wv * 1024);
    };

    stage(0, 0);
    __syncthreads();   // drains vmcnt: tile 0 + xs visible

    const int sLocal = tid & (SAMPLES_PB - 1);
    const int j      = tid >> 5;        // 0..7: LDS tree = local j, global tree = local 8+j

    int cur = 0;
    for (int c5 = 0; c5 < N_CLASSES / TSPLIT; ++c5) {
        float acc = 0.f;                // tile is single-class (class-grouped slots)
        for (int t25 = 0; t25 < TILES_PER_CLASS; ++t25) {
            const int tile = c5 * TILES_PER_CLASS + t25;
            if (tile + 1 < N_TILES) stage(tile + 1, cur ^ 1);

            const int2* nb = &nbuf[cur][j * 64];                    // LDS tree
            const size_t gslot = (size_t)(slot0 + tile * T_TILE + LDS_TREES + j);
            const int2* gp = pnodes + gslot * 64;                   // global tree

            int o0 = 0, o1 = 0;
            #pragma unroll
            for (int d = 0; d < DEPTH; ++d) {
                int2 a = nb[o0];            // ds_read_b64 (interleaved f,thr)
                int2 b = gp[o1];            // global_load_dwordx2 (L1/L2, VMEM pipe)
                float x0 = xs[a.x * SAMPLES_PB + sLocal];
                float x1 = xs[b.x * SAMPLES_PB + sLocal];
                o0 = 2 * o0 + 1 + (x0 > __int_as_float(a.y) ? 1 : 0);
                o1 = 2 * o1 + 1 + (x1 > __int_as_float(b.y) ? 1 : 0);
            }
            const size_t lslot = (size_t)(slot0 + tile * T_TILE + j);
            acc += pleaves[lslot * 64 + (o0 - N_INTERNAL)];
            acc += pleaves[gslot * 64 + (o1 - N_INTERNAL)];

            __syncthreads();   // nbuf[cur] reads done; prefetch long since landed
            cur ^= 1;
        }
        atomicAdd(&sums[sLocal * SUMS_STRIDE + cls0 + c5], acc);
    }
    __syncthreads();

    for (int e = tid; e < SAMPLES_PB * N_CLASSES; e += BLOCK) {
        int s = e / N_CLASSES, k = e - s * N_CLASSES;
        atomicAdd(&out[(size_t)(sample0 + s) * N_CLASSES + k],
                  LR * sums[s * SUMS_STRIDE + k]);
    }
}

// Fallback (ws too small): R3-style direct-global gather.
__global__ __launch_bounds__(BLOCK, 8) void gbt_eval_global(
    const float* __restrict__ x,
    const int*   __restrict__ features,
    const float* __restrict__ thresholds,
    const float* __restrict__ leaf_values,
    float*       __restrict__ out)
{
    __shared__ float xs[N_FEATURES * SAMPLES_PB];
    __shared__ float sums[SAMPLES_PB * N_CLASSES];
    const int tid = threadIdx.x;
    const int sample0 = blockIdx.x * SAMPLES_PB;
    {
        const float4* xg = (const float4*)(x + (size_t)sample0 * N_FEATURES);
        for (int e = tid; e < SAMPLES_PB * (N_FEATURES / 4); e += BLOCK) {
            int s = e >> 5, f4 = e & 31;
            float4 v = xg[e];
            int f = f4 << 2;
            xs[(f + 0) * SAMPLES_PB + s] = v.x;
            xs[(f + 1) * SAMPLES_PB + s] = v.y;
            xs[(f + 2) * SAMPLES_PB + s] = v.z;
            xs[(f + 3) * SAMPLES_PB + s] = v.w;
        }
    }
    for (int i = tid; i < SAMPLES_PB * N_CLASSES; i += BLOCK) sums[i] = 0.f;
    __syncthreads();
    const int sLocal = tid & (SAMPLES_PB - 1);
    const int j = tid >> 5;
    const int TPT = N_TREES / (8 * TSPLIT);
    const int t0 = (blockIdx.y * 8 + j) * TPT;
    float acc[N_CLASSES];
    #pragma unroll
    for (int k = 0; k < N_CLASSES; ++k) acc[k] = 0.f;
    for (int i = 0; i < TPT; i += N_CLASSES) {
        const int tt = t0 + i;
        int idx[N_CLASSES];
        #pragma unroll
        for (int u = 0; u < N_CLASSES; ++u) idx[u] = 0;
        #pragma unroll
        for (int d = 0; d < DEPTH; ++d) {
            #pragma unroll
            for (int u = 0; u < N_CLASSES; ++u) {
                int base = (tt + u) * N_INTERNAL + idx[u];
                float xv = xs[features[base] * SAMPLES_PB + sLocal];
                idx[u] = 2 * idx[u] + 1 + (xv > thresholds[base] ? 1 : 0);
            }
        }
        #pragma unroll
        for (int u = 0; u < N_CLASSES; ++u)
            acc[u] += leaf_values[(size_t)(tt + u) * 64 + idx[u] - N_INTERNAL];
    }
    #pragma unroll
    for (int k = 0; k < N_CLASSES; ++k)
        atomicAdd(&sums[sLocal * N_CLASSES + k], acc[k]);
    __syncthreads();
    for (int e = tid; e < SAMPLES_PB * N_CLASSES; e += BLOCK) {
        int s = e / N_CLASSES, k = e - s * N_CLASSES;
        atomicAdd(&out[(size_t)(sample0 + s) * N_CLASSES + k], LR * sums[e]);
    }
}

extern "C" void kernel_launch(void* const* d_in, const int* in_sizes, int n_in,
                              void* d_out, int out_size, void* d_ws, size_t ws_size,
                              hipStream_t stream) {
    const float* x          = (const float*)d_in[0];
    const int*   features   = (const int*)d_in[1];
    const float* thresholds = (const float*)d_in[2];
    const float* leafvals   = (const float*)d_in[3];
    const float* init_out   = (const float*)d_in[4];
    float*       out        = (float*)d_out;

    {
        int n = BATCH * N_CLASSES;
        out_init_kernel<<<(n + 255) / 256, 256, 0, stream>>>(init_out, out);
    }

    dim3 grid(BATCH / SAMPLES_PB, TSPLIT);  // 1024 x 2

    if (ws_size >= WS_NODES_BYTES + WS_LEAVES_BYTES) {
        int2*  pn = (int2*)d_ws;
        float* pl = (float*)((char*)d_ws + WS_NODES_BYTES);
        int n = N_TREES * 64;
        pack_kernel<<<(n + 255) / 256, 256, 0, stream>>>(features, thresholds,
                                                         leafvals, pn, pl);
        gbt_eval<<<grid, BLOCK, 0, stream>>>(x, pn, pl, out);
    } else {
        gbt_eval_global<<<grid, BLOCK, 0, stream>>>(x, features, thresholds,
                                                    leafvals, out);
    }
}